// Round 7
// baseline (17.861 us; speedup 1.0000x reference)
//
#include <hip/hip_runtime.h>

#define P 1024
#define C 8
#define D 8
#define K 8
#define GROUPS 4           // per-wave groups; each group = 2 points/lane = 128 a's
// wave handles 512 a's (half a row); 2 rows per block (4 waves)

typedef float f32x2 __attribute__((ext_vector_type(2)));

// out[n,d,b] = sum_{k,c} W[d,c,k] * T[k,c]
// T[k,c]     = sum_a basis_k(r[b,a]) * mask[b,a] * input[c,a]
// basis_k(r) = exp(-8*(r - k*2/7)^2) via telescoping:
//   t_0 = 2^64*exp(-8 r^2), t_k = t_{k-1} * B * q^(2k-1),
//   B = exp(16*(2/7)*r), q = exp(-8*(2/7)^2); mask folded as m*2^-64.
__global__ __launch_bounds__(256, 4) void se3_conv_kernel(
    const float* __restrict__ input,   // [n, C, P]
    const float* __restrict__ diff,    // [n, P, P, 3]
    const float* __restrict__ mask,    // [n, P, P]
    const float* __restrict__ W,       // [D, C, K]
    float* __restrict__ out)           // [n, D, P]
{
    __shared__ float red[4][64];

    const int n    = blockIdx.y;
    const int tid  = threadIdx.x;
    const int lane = tid & 63;
    const int wave = tid >> 6;      // 0..3
    const int rsel = wave >> 1;     // which of this block's 2 rows
    const int half = wave & 1;      // which a-half of the row
    const int b    = blockIdx.x * 2 + rsel;

    const float* diff_row = diff + (((size_t)n * P + b) * P + half * (P / 2)) * 3;
    const float* mask_row = mask + ((size_t)n * P + b) * P + half * (P / 2);
    const float* inp_n    = input + (size_t)n * C * P;

    float acc[K * C];
    #pragma unroll
    for (int i = 0; i < K * C; ++i) acc[i] = 0.0f;

    // per-group load buffers: 2 points/lane -> 6 diff + 2 mask floats
    f32x2 dv[GROUPS][3];
    f32x2 mv[GROUPS];

    // prologue: group 0 loads in flight immediately (nontemporal: no reuse)
    {
        const f32x2* p = (const f32x2*)(diff_row + (size_t)(2 * lane) * 3);
        dv[0][0] = __builtin_nontemporal_load(p + 0);
        dv[0][1] = __builtin_nontemporal_load(p + 1);
        dv[0][2] = __builtin_nontemporal_load(p + 2);
        mv[0]    = __builtin_nontemporal_load((const f32x2*)(mask_row + 2 * lane));
    }

    const float C_R2 = -11.5415603f;   // -8*log2(e)
    const float C_R  = 6.5951774f;     // 16*(2/7)*log2(e)
    const float cq[K - 1] = {           // q^(2k-1), q = exp(-8*(2/7)^2)
        0.5204502f, 0.1409736f, 0.0381853f, 0.0103432f,
        0.00280164f, 0.00075888f, 0.00020556f};

    #pragma unroll
    for (int g = 0; g < GROUPS; ++g) {
        // issue next group's streaming loads; no barrier -> counted waits
        if (g + 1 < GROUPS) {
            const int a0n = (g + 1) * 128 + 2 * lane;
            const f32x2* p = (const f32x2*)(diff_row + (size_t)a0n * 3);
            dv[g + 1][0] = __builtin_nontemporal_load(p + 0);
            dv[g + 1][1] = __builtin_nontemporal_load(p + 1);
            dv[g + 1][2] = __builtin_nontemporal_load(p + 2);
            mv[g + 1]    = __builtin_nontemporal_load((const f32x2*)(mask_row + a0n));
        }

        const int a0 = half * (P / 2) + g * 128 + 2 * lane;

        // input: cached (heavy reuse), float2 per channel covers both points
        f32x2 inp[C];
        #pragma unroll
        for (int c = 0; c < C; ++c)
            inp[c] = *(const f32x2*)(inp_n + c * P + a0);

        const float x0 = dv[g][0].x, y0 = dv[g][0].y, z0 = dv[g][1].x;
        const float x1 = dv[g][1].y, y1 = dv[g][2].x, z1 = dv[g][2].y;

        const float r2a = fmaf(x0, x0, fmaf(y0, y0, z0 * z0));
        const float r2b = fmaf(x1, x1, fmaf(y1, y1, z1 * z1));
        const float ra  = __builtin_amdgcn_sqrtf(r2a);
        const float rb  = __builtin_amdgcn_sqrtf(r2b);
        float ta        = __builtin_amdgcn_exp2f(fmaf(C_R2, r2a, 64.0f));
        float tb        = __builtin_amdgcn_exp2f(fmaf(C_R2, r2b, 64.0f));
        const float Ba  = __builtin_amdgcn_exp2f(C_R * ra);
        const float Bb  = __builtin_amdgcn_exp2f(C_R * rb);
        const float mpa = mv[g].x * 0x1p-64f;
        const float mpb = mv[g].y * 0x1p-64f;

        #pragma unroll
        for (int k = 0; k < K; ++k) {
            const float bma = ta * mpa;
            const float bmb = tb * mpb;
            #pragma unroll
            for (int c = 0; c < C; ++c) {
                float v = acc[k * C + c];
                v = fmaf(bma, inp[c].x, v);
                v = fmaf(bmb, inp[c].y, v);
                acc[k * C + c] = v;
            }
            if (k < K - 1) { ta *= (Ba * cq[k]); tb *= (Bb * cq[k]); }
        }
    }

    // ---- wave-level reduce-scatter (recursive halving) ----
    // After 6 steps lane l holds the wave-total of acc[bitrev6(l)].
    #pragma unroll
    for (int s = 0; s < 6; ++s) {
        const int hw  = 32 >> s;
        const int bit = (lane >> s) & 1;
        #pragma unroll
        for (int i = 0; i < hw; ++i) {
            const float send = bit ? acc[i] : acc[i + hw];
            const float recv = __shfl_xor(send, 1 << s, 64);
            const float keep = bit ? acc[i + hw] : acc[i];
            acc[i] = keep + recv;
        }
    }

    const int j64 = (int)(__brev((unsigned)lane) >> 26);  // bitrev6(lane)
    red[wave][j64] = acc[0];
    __syncthreads();

    // ---- combine the row's two half-waves + W contraction: lane = d*8+k ----
    if (half == 0) {
        const int d  = lane >> 3;
        const int k8 = lane & 7;
        float part = 0.0f;
        #pragma unroll
        for (int c = 0; c < C; ++c)
            part += W[d * 64 + c * 8 + k8] *
                    (red[wave][k8 * 8 + c] + red[wave + 1][k8 * 8 + c]);
        part += __shfl_xor(part, 1, 64);
        part += __shfl_xor(part, 2, 64);
        part += __shfl_xor(part, 4, 64);
        if (k8 == 0)
            out[((size_t)n * D + d) * P + b] = part;
    }
}

extern "C" void kernel_launch(void* const* d_in, const int* in_sizes, int n_in,
                              void* d_out, int out_size, void* d_ws, size_t ws_size,
                              hipStream_t stream) {
    const float* input = (const float*)d_in[0];   // [2, 8, 1024]
    const float* diff  = (const float*)d_in[1];   // [2, 1024, 1024, 3]
    const float* mask  = (const float*)d_in[2];   // [2, 1024, 1024]
    const float* W     = (const float*)d_in[3];   // [8, 8, 8]
    float* out = (float*)d_out;                   // [2, 8, 1024]

    dim3 grid(P / 2, 2);
    se3_conv_kernel<<<grid, 256, 0, stream>>>(input, diff, mask, W, out);
}

// Round 8
// 17.312 us; speedup vs baseline: 1.0317x; 1.0317x over previous
//
#include <hip/hip_runtime.h>

#define P 1024
#define C 8
#define D 8
#define K 8
#define GROUPS 4           // per-wave groups; each group = 2 points/lane = 128 a's
// wave handles 512 a's (half a row); 2 rows per block (4 waves)

typedef float f32x2 __attribute__((ext_vector_type(2)));

// out[n,d,b] = sum_{k,c} W[d,c,k] * T[k,c]
// T[k,c]     = sum_a basis_k(r[b,a]) * mask[b,a] * input[c,a]
// basis_k(r) = exp(-8*(r - k*2/7)^2) via telescoping:
//   t_0 = 2^64*exp(-8 r^2) * (m*2^-64), t_k = t_{k-1} * B * q^(2k-1),
//   B = exp(16*(2/7)*r), q = exp(-8*(2/7)^2).  Mask folded into t once.
__global__ __launch_bounds__(256, 4) void se3_conv_kernel(
    const float* __restrict__ input,   // [n, C, P]
    const float* __restrict__ diff,    // [n, P, P, 3]
    const float* __restrict__ mask,    // [n, P, P]
    const float* __restrict__ W,       // [D, C, K]
    float* __restrict__ out)           // [n, D, P]
{
    __shared__ float red[4][64];

    const int n    = blockIdx.y;
    const int tid  = threadIdx.x;
    const int lane = tid & 63;
    const int wave = tid >> 6;      // 0..3
    const int rsel = wave >> 1;     // which of this block's 2 rows
    const int half = wave & 1;      // which a-half of the row
    const int b    = blockIdx.x * 2 + rsel;

    const float* diff_row = diff + (((size_t)n * P + b) * P + half * (P / 2)) * 3;
    const float* mask_row = mask + ((size_t)n * P + b) * P + half * (P / 2);
    const float* inp_n    = input + (size_t)n * C * P;

    float acc[K * C];
    #pragma unroll
    for (int i = 0; i < K * C; ++i) acc[i] = 0.0f;

    // double-buffered load regs: 2 points/lane -> 3x f32x2 diff + 1x f32x2 mask
    f32x2 dv[2][3];
    f32x2 mv[2];

    // prologue: group 0 loads in flight immediately (normal cached loads —
    // replays are L2/L3-warm; nt was a measured regression)
    {
        const f32x2* p = (const f32x2*)(diff_row + (size_t)(2 * lane) * 3);
        dv[0][0] = p[0];
        dv[0][1] = p[1];
        dv[0][2] = p[2];
        mv[0]    = *(const f32x2*)(mask_row + 2 * lane);
    }

    const float C_R2 = -11.5415603f;   // -8*log2(e)
    const float C_R  = 6.5951774f;     // 16*(2/7)*log2(e)
    const float cq[K - 1] = {           // q^(2k-1), q = exp(-8*(2/7)^2)
        0.5204502f, 0.1409736f, 0.0381853f, 0.0103432f,
        0.00280164f, 0.00075888f, 0.00020556f};

    #pragma unroll
    for (int g = 0; g < GROUPS; ++g) {
        const int cur = g & 1;
        const int nxt = cur ^ 1;
        // issue next group's loads; no barrier -> counted vmcnt waits
        if (g + 1 < GROUPS) {
            const int a0n = (g + 1) * 128 + 2 * lane;
            const f32x2* p = (const f32x2*)(diff_row + (size_t)a0n * 3);
            dv[nxt][0] = p[0];
            dv[nxt][1] = p[1];
            dv[nxt][2] = p[2];
            mv[nxt]    = *(const f32x2*)(mask_row + a0n);
        }

        const int a0 = half * (P / 2) + g * 128 + 2 * lane;

        // input: L1/L2-hot (heavy reuse), float2 per channel covers both points
        f32x2 inp[C];
        #pragma unroll
        for (int c = 0; c < C; ++c)
            inp[c] = *(const f32x2*)(inp_n + c * P + a0);

        const float x0 = dv[cur][0].x, y0 = dv[cur][0].y, z0 = dv[cur][1].x;
        const float x1 = dv[cur][1].y, y1 = dv[cur][2].x, z1 = dv[cur][2].y;

        const float r2a = fmaf(x0, x0, fmaf(y0, y0, z0 * z0));
        const float r2b = fmaf(x1, x1, fmaf(y1, y1, z1 * z1));
        const float ra  = __builtin_amdgcn_sqrtf(r2a);
        const float rb  = __builtin_amdgcn_sqrtf(r2b);
        // mask folded into t once: saves a mul per k in the inner loop
        float ta = __builtin_amdgcn_exp2f(fmaf(C_R2, r2a, 64.0f)) * (mv[cur].x * 0x1p-64f);
        float tb = __builtin_amdgcn_exp2f(fmaf(C_R2, r2b, 64.0f)) * (mv[cur].y * 0x1p-64f);
        const float Ba = __builtin_amdgcn_exp2f(C_R * ra);
        const float Bb = __builtin_amdgcn_exp2f(C_R * rb);

        #pragma unroll
        for (int k = 0; k < K; ++k) {
            #pragma unroll
            for (int c = 0; c < C; ++c) {
                float v = acc[k * C + c];
                v = fmaf(ta, inp[c].x, v);
                v = fmaf(tb, inp[c].y, v);
                acc[k * C + c] = v;
            }
            if (k < K - 1) { ta *= (Ba * cq[k]); tb *= (Bb * cq[k]); }
        }
    }

    // ---- wave-level reduce-scatter (recursive halving) ----
    // After 6 steps lane l holds the wave-total of acc[bitrev6(l)].
    #pragma unroll
    for (int s = 0; s < 6; ++s) {
        const int hw  = 32 >> s;
        const int bit = (lane >> s) & 1;
        #pragma unroll
        for (int i = 0; i < hw; ++i) {
            const float send = bit ? acc[i] : acc[i + hw];
            const float recv = __shfl_xor(send, 1 << s, 64);
            const float keep = bit ? acc[i + hw] : acc[i];
            acc[i] = keep + recv;
        }
    }

    const int j64 = (int)(__brev((unsigned)lane) >> 26);  // bitrev6(lane)
    red[wave][j64] = acc[0];
    __syncthreads();

    // ---- combine the row's two half-waves + W contraction: lane = d*8+k ----
    if (half == 0) {
        const int d  = lane >> 3;
        const int k8 = lane & 7;
        float part = 0.0f;
        #pragma unroll
        for (int c = 0; c < C; ++c)
            part += W[d * 64 + c * 8 + k8] *
                    (red[wave][k8 * 8 + c] + red[wave + 1][k8 * 8 + c]);
        part += __shfl_xor(part, 1, 64);
        part += __shfl_xor(part, 2, 64);
        part += __shfl_xor(part, 4, 64);
        if (k8 == 0)
            out[((size_t)n * D + d) * P + b] = part;
    }
}

extern "C" void kernel_launch(void* const* d_in, const int* in_sizes, int n_in,
                              void* d_out, int out_size, void* d_ws, size_t ws_size,
                              hipStream_t stream) {
    const float* input = (const float*)d_in[0];   // [2, 8, 1024]
    const float* diff  = (const float*)d_in[1];   // [2, 1024, 1024, 3]
    const float* mask  = (const float*)d_in[2];   // [2, 1024, 1024]
    const float* W     = (const float*)d_in[3];   // [8, 8, 8]
    float* out = (float*)d_out;                   // [2, 8, 1024]

    dim3 grid(P / 2, 2);
    se3_conv_kernel<<<grid, 256, 0, stream>>>(input, diff, mask, W, out);
}

// Round 9
// 16.087 us; speedup vs baseline: 1.1103x; 1.0761x over previous
//
#include <hip/hip_runtime.h>

#define P 1024
#define C 8
#define D 8
#define K 8
#define WPB 4              // waves per block; one output row b per wave
#define NITER (P / 64)     // 16 a-iterations per lane
#define CHUNK 4
#define NCHUNK (NITER / CHUNK)

// out[n,d,b] = sum_{k,c} W[d,c,k] * T[k,c]
// T[k,c]     = sum_a basis_k(r[b,a]) * mask[b,a] * input[c,a]
// basis_k(r) = exp(-8*(r - k*2/7)^2) via telescoping:
//   t_0 = 2^64*exp(-8 r^2) * (m*2^-64), t_k = t_{k-1} * B * q^(2k-1),
//   B = exp(16*(2/7)*r), q = exp(-8*(2/7)^2).  Mask folded into t once.
// (R4 structure: LDS input + 16 pts/lane + 4-deep chunk pipeline — best
//  measured; only the basis math is changed vs R4.)
__global__ __launch_bounds__(256, 2) void se3_conv_kernel(
    const float* __restrict__ input,   // [n, C, P]
    const float* __restrict__ diff,    // [n, P, P, 3]
    const float* __restrict__ mask,    // [n, P, P]
    const float* __restrict__ W,       // [D, C, K]
    float* __restrict__ out)           // [n, D, P]
{
    __shared__ float inp_lds[C * P];   // 32 KB, input[n] staged once per block
    __shared__ float Tl[WPB][64];

    const int n    = blockIdx.y;
    const int tid  = threadIdx.x;
    const int lane = tid & 63;
    const int wave = tid >> 6;
    const int b    = blockIdx.x * WPB + wave;

    const float* diff_row = diff + (((size_t)n * P + b) * P) * 3;
    const float* mask_row = mask + ((size_t)n * P + b) * P;

    float xv[NITER], yv[NITER], zv[NITER], mv[NITER];

    // ---- chunk 0 prefetch in flight before the barrier ----
    #pragma unroll
    for (int j = 0; j < CHUNK; ++j) {
        const float* p = diff_row + (size_t)(lane + j * 64) * 3;
        xv[j] = p[0];
        yv[j] = p[1];
        zv[j] = p[2];
        mv[j] = mask_row[lane + j * 64];
    }

    // ---- stage input[n] (32 KB, L2-hot) into LDS with float4 loads ----
    {
        const float4* src = (const float4*)(input + (size_t)n * C * P);
        float4* dst = (float4*)inp_lds;
        #pragma unroll
        for (int i = 0; i < (C * P / 4) / 256; ++i)
            dst[tid + i * 256] = src[tid + i * 256];
    }

    float acc[K * C];
    #pragma unroll
    for (int i = 0; i < K * C; ++i) acc[i] = 0.0f;

    __syncthreads();   // the ONE exposed latency (staging + chunk 0)

    const float C_R2 = -11.5415603f;   // -8*log2(e)
    const float C_R  = 6.5951774f;     // 16*(2/7)*log2(e)
    const float cq[K - 1] = {           // q^(2k-1), q = exp(-8*(2/7)^2)
        0.5204502f, 0.1409736f, 0.0381853f, 0.0103432f,
        0.00280164f, 0.00075888f, 0.00020556f};

    #pragma unroll
    for (int ch = 0; ch < NCHUNK; ++ch) {
        // issue next chunk's loads; no barrier -> counted vmcnt waits,
        // these stream while we compute the current chunk
        if (ch + 1 < NCHUNK) {
            #pragma unroll
            for (int jj = 0; jj < CHUNK; ++jj) {
                const int j = (ch + 1) * CHUNK + jj;
                const float* p = diff_row + (size_t)(lane + j * 64) * 3;
                xv[j] = p[0];
                yv[j] = p[1];
                zv[j] = p[2];
                mv[j] = mask_row[lane + j * 64];
            }
        }

        #pragma unroll
        for (int jj = 0; jj < CHUNK; ++jj) {
            const int j = ch * CHUNK + jj;
            const int a = lane + j * 64;
            const float x = xv[j], y = yv[j], z = zv[j];

            const float r2 = fmaf(x, x, fmaf(y, y, z * z));
            const float r  = __builtin_amdgcn_sqrtf(r2);
            // mask folded into t once; 2^64 offset keeps chain normal
            float t = __builtin_amdgcn_exp2f(fmaf(C_R2, r2, 64.0f)) *
                      (mv[j] * 0x1p-64f);
            const float B = __builtin_amdgcn_exp2f(C_R * r);

            float inp[C];
            #pragma unroll
            for (int c = 0; c < C; ++c) inp[c] = inp_lds[c * P + a];

            #pragma unroll
            for (int k = 0; k < K; ++k) {
                #pragma unroll
                for (int c = 0; c < C; ++c)
                    acc[k * C + c] = fmaf(t, inp[c], acc[k * C + c]);
                if (k < K - 1) t *= (B * cq[k]);
            }
        }
    }

    // ---- wave-level reduce-scatter (recursive halving) ----
    // After 6 steps lane l holds the wave-total of acc[bitrev6(l)].
    #pragma unroll
    for (int s = 0; s < 6; ++s) {
        const int hw  = 32 >> s;
        const int bit = (lane >> s) & 1;
        #pragma unroll
        for (int i = 0; i < hw; ++i) {
            const float send = bit ? acc[i] : acc[i + hw];
            const float recv = __shfl_xor(send, 1 << s, 64);
            const float keep = bit ? acc[i + hw] : acc[i];
            acc[i] = keep + recv;
        }
    }

    const int j64 = (int)(__brev((unsigned)lane) >> 26);  // bitrev6(lane)
    Tl[wave][j64] = acc[0];
    __syncthreads();   // uniform; orders per-wave LDS write vs read

    // ---- parallel W contraction: lane = d*8 + k8 ----
    const int d  = lane >> 3;
    const int k8 = lane & 7;
    float part = 0.0f;
    #pragma unroll
    for (int q = 0; q < 8; ++q)
        part += W[d * 64 + q * 8 + k8] * Tl[wave][k8 * 8 + q];
    part += __shfl_xor(part, 1, 64);
    part += __shfl_xor(part, 2, 64);
    part += __shfl_xor(part, 4, 64);
    if (k8 == 0)
        out[((size_t)n * D + d) * P + b] = part;
}

extern "C" void kernel_launch(void* const* d_in, const int* in_sizes, int n_in,
                              void* d_out, int out_size, void* d_ws, size_t ws_size,
                              hipStream_t stream) {
    const float* input = (const float*)d_in[0];   // [2, 8, 1024]
    const float* diff  = (const float*)d_in[1];   // [2, 1024, 1024, 3]
    const float* mask  = (const float*)d_in[2];   // [2, 1024, 1024]
    const float* W     = (const float*)d_in[3];   // [8, 8, 8]
    float* out = (float*)d_out;                   // [2, 8, 1024]

    dim3 grid(P / WPB, 2);
    se3_conv_kernel<<<grid, 256, 0, stream>>>(input, diff, mask, W, out);
}

// Round 10
// 15.186 us; speedup vs baseline: 1.1761x; 1.0593x over previous
//
#include <hip/hip_runtime.h>

#define P 1024
#define C 8
#define D 8
#define K 8
#define WPB 4              // waves per block; one output row b per wave
#define NITER (P / 64)     // 16 a-iterations per lane
#define CHUNK 4
#define NCHUNK (NITER / CHUNK)
#define AHEAD 2            // chunks issued ahead of compute (covers ~900cy HBM)

// out[n,d,b] = sum_{k,c} W[d,c,k] * T[k,c]
// T[k,c]     = sum_a exp(-8*(r[b,a]-ck)^2) * mask[b,a] * input[c,a]
// R4 base (best measured: 14.9us) with ONE change: 2-chunk-ahead prefetch.
// Basis = 8 independent exp2 (R9's telescoped chain regressed; reverted).
__global__ __launch_bounds__(256, 2) void se3_conv_kernel(
    const float* __restrict__ input,   // [n, C, P]
    const float* __restrict__ diff,    // [n, P, P, 3]
    const float* __restrict__ mask,    // [n, P, P]
    const float* __restrict__ W,       // [D, C, K]
    float* __restrict__ out)           // [n, D, P]
{
    __shared__ float inp_lds[C * P];   // 32 KB, input[n] staged once per block
    __shared__ float Tl[WPB][64];

    const int n    = blockIdx.y;
    const int tid  = threadIdx.x;
    const int lane = tid & 63;
    const int wave = tid >> 6;
    const int b    = blockIdx.x * WPB + wave;

    const float* diff_row = diff + (((size_t)n * P + b) * P) * 3;
    const float* mask_row = mask + ((size_t)n * P + b) * P;

    float xv[NITER], yv[NITER], zv[NITER], mv[NITER];

    // ---- chunks 0..AHEAD-1 in flight before the barrier ----
    #pragma unroll
    for (int j = 0; j < AHEAD * CHUNK; ++j) {
        const float* p = diff_row + (size_t)(lane + j * 64) * 3;
        xv[j] = p[0];
        yv[j] = p[1];
        zv[j] = p[2];
        mv[j] = mask_row[lane + j * 64];
    }

    // ---- stage input[n] (32 KB, L2-hot) into LDS with float4 loads ----
    {
        const float4* src = (const float4*)(input + (size_t)n * C * P);
        float4* dst = (float4*)inp_lds;
        #pragma unroll
        for (int i = 0; i < (C * P / 4) / 256; ++i)
            dst[tid + i * 256] = src[tid + i * 256];
    }

    float acc[K * C];
    #pragma unroll
    for (int i = 0; i < K * C; ++i) acc[i] = 0.0f;

    __syncthreads();   // the ONE exposed latency (staging + first chunks)

    const float L2E = 1.44269504f;
    // basis_k(r)*m = exp2( -8*L2E*r^2 + fma(16*L2E*ck, r, -8*L2E*ck^2) ) * m

    #pragma unroll
    for (int ch = 0; ch < NCHUNK; ++ch) {
        // issue chunk ch+AHEAD's loads; no barrier -> counted vmcnt waits;
        // two full compute phases (~1300cy) cover the ~900cy HBM latency
        if (ch + AHEAD < NCHUNK) {
            #pragma unroll
            for (int jj = 0; jj < CHUNK; ++jj) {
                const int j = (ch + AHEAD) * CHUNK + jj;
                const float* p = diff_row + (size_t)(lane + j * 64) * 3;
                xv[j] = p[0];
                yv[j] = p[1];
                zv[j] = p[2];
                mv[j] = mask_row[lane + j * 64];
            }
        }

        #pragma unroll
        for (int jj = 0; jj < CHUNK; ++jj) {
            const int j = ch * CHUNK + jj;
            const int a = lane + j * 64;
            const float x = xv[j], y = yv[j], z = zv[j], m = mv[j];

            const float r2 = fmaf(x, x, fmaf(y, y, z * z));
            const float r  = __builtin_amdgcn_sqrtf(r2);
            const float u  = -8.0f * L2E * r2;

            float basis[K];
            #pragma unroll
            for (int k = 0; k < K; ++k) {
                const float ck = (2.0f / 7.0f) * (float)k;
                const float c1 = 16.0f * L2E * ck;
                const float c0 = -8.0f * L2E * ck * ck;
                basis[k] = __builtin_amdgcn_exp2f(fmaf(c1, r, u + c0)) * m;
            }

            float inp[C];
            #pragma unroll
            for (int c = 0; c < C; ++c) inp[c] = inp_lds[c * P + a];

            #pragma unroll
            for (int k = 0; k < K; ++k)
                #pragma unroll
                for (int c = 0; c < C; ++c)
                    acc[k * C + c] = fmaf(basis[k], inp[c], acc[k * C + c]);
        }
    }

    // ---- wave-level reduce-scatter (recursive halving) ----
    // After 6 steps lane l holds the wave-total of acc[bitrev6(l)].
    #pragma unroll
    for (int s = 0; s < 6; ++s) {
        const int hw  = 32 >> s;
        const int bit = (lane >> s) & 1;
        #pragma unroll
        for (int i = 0; i < hw; ++i) {
            const float send = bit ? acc[i] : acc[i + hw];
            const float recv = __shfl_xor(send, 1 << s, 64);
            const float keep = bit ? acc[i + hw] : acc[i];
            acc[i] = keep + recv;
        }
    }

    const int j64 = (int)(__brev((unsigned)lane) >> 26);  // bitrev6(lane)
    Tl[wave][j64] = acc[0];
    __syncthreads();   // uniform; orders per-wave LDS write vs read

    // ---- parallel W contraction: lane = d*8 + k8 ----
    const int d  = lane >> 3;
    const int k8 = lane & 7;
    float part = 0.0f;
    #pragma unroll
    for (int q = 0; q < 8; ++q)
        part += W[d * 64 + q * 8 + k8] * Tl[wave][k8 * 8 + q];
    part += __shfl_xor(part, 1, 64);
    part += __shfl_xor(part, 2, 64);
    part += __shfl_xor(part, 4, 64);
    if (k8 == 0)
        out[((size_t)n * D + d) * P + b] = part;
}

extern "C" void kernel_launch(void* const* d_in, const int* in_sizes, int n_in,
                              void* d_out, int out_size, void* d_ws, size_t ws_size,
                              hipStream_t stream) {
    const float* input = (const float*)d_in[0];   // [2, 8, 1024]
    const float* diff  = (const float*)d_in[1];   // [2, 1024, 1024, 3]
    const float* mask  = (const float*)d_in[2];   // [2, 1024, 1024]
    const float* W     = (const float*)d_in[3];   // [8, 8, 8]
    float* out = (float*)d_out;                   // [2, 8, 1024]

    dim3 grid(P / WPB, 2);
    se3_conv_kernel<<<grid, 256, 0, stream>>>(input, diff, mask, W, out);
}